// Round 2
// baseline (1114.186 us; speedup 1.0000x reference)
//
#include <hip/hip_runtime.h>

// DRNet, R13: VALU instruction diet via packed-fp32 (VOP3P) + branchless
// erfinv/tanh. R12's null (955us, counters unchanged) falsified the
// phase-serialization theory: VALUBusy ~88% is real issue saturation and the
// kernel sits on the ~900us device VALU-issue wall (prior session: RNG-only
// kernel = 697us @92% issue efficiency; total is partition-invariant). The
// only remaining lever is fewer VALU instructions at identical bits:
//  - erfinv finish (u/t1/s/w/polys/p*u) packed 2 samples per instr with
//    v_pk_fma_f32 / v_pk_add_f32 / v_pk_mul_f32 (per-component IEEE fp32,
//    bit-identical to the scalar ops they replace)
//  - BOTH erfinv polynomials computed unconditionally (packed), then
//    per-component select -- deletes the divergent w<5 branch entirely
//  - tanh clamp made branchless (always exp2/rcp, cndmask the clamp) --
//    selected values bit-identical; exp2 overflow path yields finite junk
//    that the select discards
//  - tail (d, pre, e+1, h, nl, apply-noise, low-split) packed pairwise
// Threefry int ops (~288/thread-step) are irreducible: no packed u32 ALU.
// Keeps R12's cross-barrier RNG pipeline (neutral, structurally clean),
// LDS layout, MFMA loop, and write layout. Numerics bit-identical.

#define TSTEPS 256
#define HDIM   256
#define ROWS   16
#define LSTR   264            // shorts per tile row (pad 8)
#define TILE   (ROWS * LSTR)  // 4224 shorts = 8448 B per level

typedef _Float16 half8 __attribute__((ext_vector_type(8)));
typedef __attribute__((ext_vector_type(4))) float float4v;
typedef __attribute__((ext_vector_type(2))) float float2v;

struct U2 { unsigned x, y; };

__device__ __forceinline__ float2v sp(float x) { return (float2v){x, x}; }

__device__ __forceinline__ void tfround(unsigned &x0, unsigned &x1, const int r) {
  x0 += x1;
  x1 = __builtin_rotateleft32(x1, r);
  x1 ^= x0;
}

// Threefry-2x32, 20 rounds (Random123 / JAX threefry2x32_p)
__device__ __forceinline__ U2 threefry(unsigned k0, unsigned k1, unsigned x0, unsigned x1) {
  unsigned k2 = k0 ^ k1 ^ 0x1BD11BDAu;
  x0 += k0; x1 += k1;
  tfround(x0,x1,13); tfround(x0,x1,15); tfround(x0,x1,26); tfround(x0,x1,6);
  x0 += k1; x1 += k2 + 1u;
  tfround(x0,x1,17); tfround(x0,x1,29); tfround(x0,x1,16); tfround(x0,x1,24);
  x0 += k2; x1 += k0 + 2u;
  tfround(x0,x1,13); tfround(x0,x1,15); tfround(x0,x1,26); tfround(x0,x1,6);
  x0 += k0; x1 += k1 + 3u;
  tfround(x0,x1,17); tfround(x0,x1,29); tfround(x0,x1,16); tfround(x0,x1,24);
  x0 += k1; x1 += k2 + 4u;
  tfround(x0,x1,13); tfround(x0,x1,15); tfround(x0,x1,26); tfround(x0,x1,6);
  x0 += k2; x1 += k0 + 5u;
  return {x0, x1};
}

// Packed 2-sample JAX normal: uniform(nextafter(-1,0),1) -> sqrt2*erfinv(u),
// XLA ErfInv32. Per-component ops map 1:1 onto the scalar version (IEEE
// fp32 packed == scalar); both polys computed, per-component select.
__device__ __forceinline__ float2v jax_normal2(unsigned b0, unsigned b1) {
#pragma clang fp contract(off)
  const float LO = __builtin_bit_cast(float, 0xBF7FFFFFu); // nextafter(-1,0)
  float2v f;
  f.x = __builtin_bit_cast(float, (b0 >> 9) | 0x3f800000u);
  f.y = __builtin_bit_cast(float, (b1 >> 9) | 0x3f800000u);
  f = f - sp(1.0f);
  float2v u = __builtin_elementwise_fma(f, sp(2.0f), sp(LO));
  u = __builtin_elementwise_max(u, sp(LO));
  float2v t1 = u * u;            // rounded u^2 (as XLA's x*x)
  float2v s  = sp(1.0f) - t1;    // Sterbenz-exact in the tail; unfused
  float2v lg;
  lg.x = __builtin_amdgcn_logf(s.x);
  lg.y = __builtin_amdgcn_logf(s.y);
  float2v w = sp(-0.6931471805599453f) * lg;

  // main branch (w < 5)
  float2v z1 = w - sp(2.5f);
  float2v pm = sp(2.81022636e-08f);
  pm = __builtin_elementwise_fma(pm, z1, sp(3.43273939e-07f));
  pm = __builtin_elementwise_fma(pm, z1, sp(-3.5233877e-06f));
  pm = __builtin_elementwise_fma(pm, z1, sp(-4.39150654e-06f));
  pm = __builtin_elementwise_fma(pm, z1, sp(0.00021858087f));
  pm = __builtin_elementwise_fma(pm, z1, sp(-0.00125372503f));
  pm = __builtin_elementwise_fma(pm, z1, sp(-0.00417768164f));
  pm = __builtin_elementwise_fma(pm, z1, sp(0.246640727f));
  pm = __builtin_elementwise_fma(pm, z1, sp(1.50140941f));

  // rare branch (w >= 5): computed unconditionally, selected away below.
  // w > 0 always (s in (0,1]); sqrt finite.
  float2v z2;
  z2.x = sqrtf(w.x);
  z2.y = sqrtf(w.y);
  z2 = z2 - sp(3.0f);
  float2v pr = sp(-0.000200214257f);
  pr = __builtin_elementwise_fma(pr, z2, sp(0.000100950558f));
  pr = __builtin_elementwise_fma(pr, z2, sp(0.00134934322f));
  pr = __builtin_elementwise_fma(pr, z2, sp(-0.00367342844f));
  pr = __builtin_elementwise_fma(pr, z2, sp(0.00573950773f));
  pr = __builtin_elementwise_fma(pr, z2, sp(-0.0076224613f));
  pr = __builtin_elementwise_fma(pr, z2, sp(0.00943887047f));
  pr = __builtin_elementwise_fma(pr, z2, sp(1.00167406f));
  pr = __builtin_elementwise_fma(pr, z2, sp(2.83297682f));

  float2v p;
  p.x = (w.x < 5.0f) ? pm.x : pr.x;
  p.y = (w.y < 5.0f) ? pm.y : pr.y;
  float2v pu = p * u;
  return sp(1.4142135623730951f) * pu;
}

__device__ __forceinline__ float4v mfma_f16(half8 a, half8 b, float4v c) {
  return __builtin_amdgcn_mfma_f32_16x16x32_f16(a, b, c, 0, 0, 0);
}

__global__ __launch_bounds__(1024, 4)
void drnet_fused(const float* __restrict__ flat_img,
                 const float* __restrict__ W_ih,
                 const float* __restrict__ W_hh,
                 const float* __restrict__ b_ih,
                 const float* __restrict__ b_hh,
                 float* __restrict__ out)
{
  // >81920 B -> 1 block/CU -> exactly 4 waves/EU -> 128-reg budget
  // (VGPR ~60 + 64 weight AGPRs; must stay <= 128 unified, watch for spill)
  __shared__ __align__(16) char lds_pool[86016];
  float*    x_tr    = (float*)lds_pool;               // [t][row] 16384 B
  unsigned* keys_sh = (unsigned*)(lds_pool + 16384);  // 2064 B (257 pairs)
  float*    esc_sh  = (float*)(lds_pool + 18448);     // 1024 B
  short*    latp    = (short*)(lds_pool + 19472);     // 2 buf x 2 lv x TILE

  const int tid  = threadIdx.x;
  const int wg   = blockIdx.x;
  const int wv   = tid >> 6;     // wave owns cols [wv*16, wv*16+16)
  const int lane = tid & 63;
  const int q    = lane >> 4;
  const int c    = lane & 15;

  // key_t = threefry((0,42), (0,t)); entry 256 pads the t=255 dead
  // generation (finite, never applied). escale table.
  if (tid <= TSTEPS) {
    U2 kk2 = threefry(0u, 42u, 0u, (unsigned)tid);
    keys_sh[2*tid]   = kk2.x;
    keys_sh[2*tid+1] = kk2.y;
    if (tid < TSTEPS) {
      float tsf = (float)(TSTEPS - tid);
      float a_t = (tsf + 1.0f) / 257.0f;
      esc_sh[tid] = 0.1f * sqrtf(a_t * (1.0f - a_t));  // exactly 0 at t=0
    }
  }

  { // stage x TRANSPOSED: x_tr[t*16 + row] = flat_img[wg*16+row][t]
    int i = tid * 4;                 // 4 consecutive t of one row
    int m = i >> 8;
    float4v v = *(const float4v*)(flat_img + (size_t)wg * (ROWS*TSTEPS) + i);
    int tbase = i & 255;
    #pragma unroll
    for (int s = 0; s < 4; ++s) x_tr[(tbase + s) * ROWS + m] = v[s];
  }

  { // zero latent: 2 buf x 2 lv x TILE shorts == 2*TILE ints
    int* p0 = (int*)latp;
    for (int i = tid; i < 2 * TILE; i += 1024) p0[i] = 0;
  }

  // persistent W_hh fragments: 2-level fp16 split (level-1 scaled 2^11)
  half8 Wh[8], Wl[8];
  const int g = wv*16 + c;
  const float bias = b_ih[g] + b_hh[g];
  const float wih  = W_ih[g];
  #pragma unroll
  for (int kk = 0; kk < 8; ++kk) {
    const float* wp = W_hh + g*HDIM + kk*32 + q*8;
    float4v w0 = *(const float4v*)wp;
    float4v w1 = *(const float4v*)(wp + 4);
    half8 h8, l8;
    #pragma unroll
    for (int j2 = 0; j2 < 4; ++j2) {
      float f0 = w0[j2], f1 = w1[j2];
      _Float16 h0 = (_Float16)f0, h1 = (_Float16)f1;
      _Float16 l0 = (_Float16)((f0 - (float)h0) * 2048.0f);
      _Float16 l1 = (_Float16)((f1 - (float)h1) * 2048.0f);
      h8[j2] = h0; h8[j2+4] = h1;
      l8[j2] = l0; l8[j2+4] = l1;
    }
    Wh[kk] = h8; Wl[kk] = l8;
  }

  // fp32 master latent: lane owns rows q*4+r (r<4), col g -- held as 2 pairs
  float2v latA = {0.f, 0.f}, latB = {0.f, 0.f};
  // pipelined noise for the CURRENT step (generated during the previous one);
  // t=0 uses zeros with esc[0]==0 -> fmaf(0,0,lat)==lat, bit-exact.
  float2v nrm01 = {0.f, 0.f}, nrm23 = {0.f, 0.f};
  const unsigned jbase = ((unsigned)(wg*ROWS + q*4) << 8) + (unsigned)g;
  const int aoff = c * LSTR + q * 8;          // A-frag: A[m=lane&15][k=q*8+j]
  const int woff = (q*4) * LSTR + wv*16 + c;  // write base (shorts)

  __syncthreads();

  for (int t = 0; t < TSTEPS; ++t) {
    // apply the noise generated last step (keys[2t] pairing preserved)
    float escale = esc_sh[t];
    latA = __builtin_elementwise_fma(sp(escale), nrm01, latA);
    latB = __builtin_elementwise_fma(sp(escale), nrm23, latB);

    // keys for NEXT step's noise (pipelined across the barrier)
    unsigned kA = (unsigned)__builtin_amdgcn_readfirstlane((int)keys_sh[2*t+2]);
    unsigned kB = (unsigned)__builtin_amdgcn_readfirstlane((int)keys_sh[2*t+3]);

    // x for rows q*4..q*4+3 at time t: one broadcast ds_read_b128
    float4v xv = *(const float4v*)&x_tr[t * ROWS + q * 4];

    const short* rb = latp + (t & 1) * (2*TILE) + aoff;
    short*       wb = latp + ((t + 1) & 1) * (2*TILE) + woff;

    // AhWh -> aa ; (AlWh + AhWl) -> ab (one 2^11 scale); drop AlWl ~2^-24.
    // Cipher pairs for step t+1 interleaved at kk 0 and 4; the packed
    // erfinv finish overlaps the matrix pipe.
    float4v aa = {0.f, 0.f, 0.f, 0.f};
    float4v ab = {0.f, 0.f, 0.f, 0.f};
    #pragma unroll
    for (int kk = 0; kk < 8; ++kk) {
      half8 ah = *(const half8*)(rb + 0*TILE + kk*32);
      half8 al = *(const half8*)(rb + 1*TILE + kk*32);
      aa = mfma_f16(ah, Wh[kk], aa);
      ab = mfma_f16(al, Wh[kk], ab);
      ab = mfma_f16(ah, Wl[kk], ab);
      if (kk == 0) {   // samples r=0,1: j = jbase + {0,256}
        U2 r0 = threefry(kA, kB, 0u, jbase);
        U2 r1 = threefry(kA, kB, 0u, jbase + 256u);
        nrm01 = jax_normal2(r0.x ^ r0.y, r1.x ^ r1.y);
      }
      if (kk == 4) {   // samples r=2,3: j = jbase + {512,768}
        U2 r2 = threefry(kA, kB, 0u, jbase + 512u);
        U2 r3 = threefry(kA, kB, 0u, jbase + 768u);
        nrm23 = jax_normal2(r2.x ^ r2.y, r3.x ^ r3.y);
      }
    }

    // packed tail: per-component ops bit-identical to the scalar R12 tail
    float2v xv01 = {xv[0], xv[1]}, xv23 = {xv[2], xv[3]};
    float2v aa01 = {aa[0], aa[1]}, aa23 = {aa[2], aa[3]};
    float2v ab01 = {ab[0], ab[1]}, ab23 = {ab[2], ab[3]};
    float2v d01 = __builtin_elementwise_fma(ab01, sp(1.0f/2048.0f), aa01);
    float2v d23 = __builtin_elementwise_fma(ab23, sp(1.0f/2048.0f), aa23);
    float2v pre01 = d01 + __builtin_elementwise_fma(xv01, sp(wih), sp(bias));
    float2v pre23 = d23 + __builtin_elementwise_fma(xv23, sp(wih), sp(bias));

    // branchless tanh: always compute, cndmask the XLA clamp. Overflowed
    // exp2 gives finite garbage that the select discards (no NaN: e+1>=1).
    float2v arg01 = pre01 * sp(2.8853900817779268f);
    float2v arg23 = pre23 * sp(2.8853900817779268f);
    float2v e01, e23;
    e01.x = __builtin_amdgcn_exp2f(arg01.x);
    e01.y = __builtin_amdgcn_exp2f(arg01.y);
    e23.x = __builtin_amdgcn_exp2f(arg23.x);
    e23.y = __builtin_amdgcn_exp2f(arg23.y);
    float2v ep01 = e01 + sp(1.0f);
    float2v ep23 = e23 + sp(1.0f);
    float2v rc01, rc23;
    rc01.x = __builtin_amdgcn_rcpf(ep01.x);
    rc01.y = __builtin_amdgcn_rcpf(ep01.y);
    rc23.x = __builtin_amdgcn_rcpf(ep23.x);
    rc23.y = __builtin_amdgcn_rcpf(ep23.y);
    float2v th01 = __builtin_elementwise_fma(sp(-2.0f), rc01, sp(1.0f));
    float2v th23 = __builtin_elementwise_fma(sp(-2.0f), rc23, sp(1.0f));
    const float TCL = 7.90531110763549805f;
    float2v h01, h23;
    h01.x = (__builtin_fabsf(pre01.x) >= TCL) ? (pre01.x > 0.0f ? 1.0f : -1.0f) : th01.x;
    h01.y = (__builtin_fabsf(pre01.y) >= TCL) ? (pre01.y > 0.0f ? 1.0f : -1.0f) : th01.y;
    h23.x = (__builtin_fabsf(pre23.x) >= TCL) ? (pre23.x > 0.0f ? 1.0f : -1.0f) : th23.x;
    h23.y = (__builtin_fabsf(pre23.y) >= TCL) ? (pre23.y > 0.0f ? 1.0f : -1.0f) : th23.y;

    float2v nl01 = (latA + xv01) + h01;   // same left-assoc order as scalar
    float2v nl23 = (latB + xv23) + h23;
    latA = nl01;
    latB = nl23;

    // fp16 2-level split + LDS writes (cvt stays scalar: RNE v_cvt_f16_f32)
    _Float16 hh0 = (_Float16)nl01.x, hh1 = (_Float16)nl01.y;
    _Float16 hh2 = (_Float16)nl23.x, hh3 = (_Float16)nl23.y;
    float2v bk01 = {(float)hh0, (float)hh1};
    float2v bk23 = {(float)hh2, (float)hh3};
    float2v lo01 = (nl01 - bk01) * sp(2048.0f);
    float2v lo23 = (nl23 - bk23) * sp(2048.0f);
    _Float16 ll0 = (_Float16)lo01.x, ll1 = (_Float16)lo01.y;
    _Float16 ll2 = (_Float16)lo23.x, ll3 = (_Float16)lo23.y;
    wb[0*LSTR]        = __builtin_bit_cast(short, hh0);
    wb[0*LSTR + TILE] = __builtin_bit_cast(short, ll0);
    wb[1*LSTR]        = __builtin_bit_cast(short, hh1);
    wb[1*LSTR + TILE] = __builtin_bit_cast(short, ll1);
    wb[2*LSTR]        = __builtin_bit_cast(short, hh2);
    wb[2*LSTR + TILE] = __builtin_bit_cast(short, ll2);
    wb[3*LSTR]        = __builtin_bit_cast(short, hh3);
    wb[3*LSTR + TILE] = __builtin_bit_cast(short, ll3);

    __syncthreads(); // single barrier/step (reads buf t&1, writes (t+1)&1)
  }

  out[jbase]        = latA.x;
  out[jbase + 256u] = latA.y;
  out[jbase + 512u] = latB.x;
  out[jbase + 768u] = latB.y;
}

extern "C" void kernel_launch(void* const* d_in, const int* in_sizes, int n_in,
                              void* d_out, int out_size, void* d_ws, size_t ws_size,
                              hipStream_t stream) {
  // inputs: [0]=T (int, =256), [1]=flat_img (4096x256 f32), [2]=W_ih (256x1),
  // [3]=W_hh (256x256), [4]=b_ih (256), [5]=b_hh (256)
  (void)in_sizes; (void)n_in; (void)out_size; (void)d_ws; (void)ws_size;
  const float* flat_img = (const float*)d_in[1];
  const float* W_ih     = (const float*)d_in[2];
  const float* W_hh     = (const float*)d_in[3];
  const float* b_ih     = (const float*)d_in[4];
  const float* b_hh     = (const float*)d_in[5];
  drnet_fused<<<dim3(4096 / ROWS), dim3(1024), 0, stream>>>(
      flat_img, W_ih, W_hh, b_ih, b_hh, (float*)d_out);
}

// Round 4
// 957.866 us; speedup vs baseline: 1.1632x; 1.1632x over previous
//
#include <hip/hip_runtime.h>

// DRNet, R15: fix R14's swizzle wrap bug. R14's whole-row rotation
// ((col+16*(row>>2))&255) wrapped mod 256 while the read path added kk*32
// linearly -> reads escaped into the row pad for high c,kk (absmax 510).
// R15 rotates SLOTS WITHIN each 32-short block: col -> block b=col>>5,
// slot sl=(col>>3)&3, j=col&7; stored at row*LSTR + b*32 +
// ((sl + (row>>2))&3)*8 + j. Wrap is confined to the block; reads stay
// contiguous & 16B-aligned (max in-row offset 255).
//  - write bank = (16q+4r+16(wv>>1)+4*((sl+q)&3)+(c>>1 within 8)) mod 32:
//    enumerated over all 64 lanes (both wv parities) = all 32 banks x
//    exactly 2 lanes -> 2-way, free (was 4-way).
//  - read bank-base 4*((c+(q+(c>>2))&3)&7): 8 lanes per 4-bank group,
//    same perfect balance as the unrotated read.
// Pure storage bijection (t=0 tile zeros) -> bit-identical numerics.
// Rest identical to R12 (955us): cross-barrier RNG pipeline, per-kk cipher
// interleave, divergent-but-rare erfinv branch (R13's branchless packed
// version regressed 16%).

#define TSTEPS 256
#define HDIM   256
#define ROWS   16
#define LSTR   264            // shorts per tile row (pad 8)
#define TILE   (ROWS * LSTR)  // 4224 shorts = 8448 B per level

typedef _Float16 half8 __attribute__((ext_vector_type(8)));
typedef __attribute__((ext_vector_type(4))) float float4v;

struct U2 { unsigned x, y; };

__device__ __forceinline__ void tfround(unsigned &x0, unsigned &x1, const int r) {
  x0 += x1;
  x1 = __builtin_rotateleft32(x1, r);
  x1 ^= x0;
}

// Threefry-2x32, 20 rounds (Random123 / JAX threefry2x32_p)
__device__ __forceinline__ U2 threefry(unsigned k0, unsigned k1, unsigned x0, unsigned x1) {
  unsigned k2 = k0 ^ k1 ^ 0x1BD11BDAu;
  x0 += k0; x1 += k1;
  tfround(x0,x1,13); tfround(x0,x1,15); tfround(x0,x1,26); tfround(x0,x1,6);
  x0 += k1; x1 += k2 + 1u;
  tfround(x0,x1,17); tfround(x0,x1,29); tfround(x0,x1,16); tfround(x0,x1,24);
  x0 += k2; x1 += k0 + 2u;
  tfround(x0,x1,13); tfround(x0,x1,15); tfround(x0,x1,26); tfround(x0,x1,6);
  x0 += k0; x1 += k1 + 3u;
  tfround(x0,x1,17); tfround(x0,x1,29); tfround(x0,x1,16); tfround(x0,x1,24);
  x0 += k1; x1 += k2 + 4u;
  tfround(x0,x1,13); tfround(x0,x1,15); tfround(x0,x1,26); tfround(x0,x1,6);
  x0 += k2; x1 += k0 + 5u;
  return {x0, x1};
}

// JAX uniform(lo=nextafter(-1,0), 1) -> sqrt(2)*erf_inv(u), XLA ErfInv32.
__device__ __forceinline__ float jax_normal_from_bits(unsigned bits) {
#pragma clang fp contract(off)
  const float LO = __builtin_bit_cast(float, 0xBF7FFFFFu); // nextafter(-1,0)
  float f = __builtin_bit_cast(float, (bits >> 9) | 0x3f800000u) - 1.0f;
  float u = fmaf(f, 2.0f, LO);
  u = fmaxf(u, LO);
  float t1 = u * u;             // rounded u^2 (as XLA's x*x)
  float s  = 1.0f - t1;         // Sterbenz-exact in the tail; unfused
  float w  = -0.6931471805599453f * __builtin_amdgcn_logf(s);
  float p;
  if (w < 5.0f) {
    float z = w - 2.5f;
    p = 2.81022636e-08f;
    p = fmaf(p, z, 3.43273939e-07f);
    p = fmaf(p, z, -3.5233877e-06f);
    p = fmaf(p, z, -4.39150654e-06f);
    p = fmaf(p, z, 0.00021858087f);
    p = fmaf(p, z, -0.00125372503f);
    p = fmaf(p, z, -0.00417768164f);
    p = fmaf(p, z, 0.246640727f);
    p = fmaf(p, z, 1.50140941f);
  } else {
    float z = sqrtf(w) - 3.0f;
    p = -0.000200214257f;
    p = fmaf(p, z, 0.000100950558f);
    p = fmaf(p, z, 0.00134934322f);
    p = fmaf(p, z, -0.00367342844f);
    p = fmaf(p, z, 0.00573950773f);
    p = fmaf(p, z, -0.0076224613f);
    p = fmaf(p, z, 0.00943887047f);
    p = fmaf(p, z, 1.00167406f);
    p = fmaf(p, z, 2.83297682f);
  }
  return 1.4142135623730951f * (p * u);
}

__device__ __forceinline__ float4v mfma_f16(half8 a, half8 b, float4v c) {
  return __builtin_amdgcn_mfma_f32_16x16x32_f16(a, b, c, 0, 0, 0);
}

__global__ __launch_bounds__(1024, 4)
void drnet_fused(const float* __restrict__ flat_img,
                 const float* __restrict__ W_ih,
                 const float* __restrict__ W_hh,
                 const float* __restrict__ b_ih,
                 const float* __restrict__ b_hh,
                 float* __restrict__ out)
{
  // >81920 B -> 1 block/CU -> exactly 4 waves/EU -> 128-reg budget
  __shared__ __align__(16) char lds_pool[86016];
  float*    x_tr    = (float*)lds_pool;               // [t][row] 16384 B
  unsigned* keys_sh = (unsigned*)(lds_pool + 16384);  // 2064 B (257 pairs)
  float*    esc_sh  = (float*)(lds_pool + 18448);     // 1024 B
  short*    latp    = (short*)(lds_pool + 19472);     // 2 buf x 2 lv x TILE

  const int tid  = threadIdx.x;
  const int wg   = blockIdx.x;
  const int wv   = tid >> 6;     // wave owns cols [wv*16, wv*16+16)
  const int lane = tid & 63;
  const int q    = lane >> 4;
  const int c    = lane & 15;

  // key_t = threefry((0,42), (0,t)); entry 256 pads the t=255 dead
  // generation (finite, never applied). escale table.
  if (tid <= TSTEPS) {
    U2 kk2 = threefry(0u, 42u, 0u, (unsigned)tid);
    keys_sh[2*tid]   = kk2.x;
    keys_sh[2*tid+1] = kk2.y;
    if (tid < TSTEPS) {
      float tsf = (float)(TSTEPS - tid);
      float a_t = (tsf + 1.0f) / 257.0f;
      esc_sh[tid] = 0.1f * sqrtf(a_t * (1.0f - a_t));  // exactly 0 at t=0
    }
  }

  { // stage x TRANSPOSED: x_tr[t*16 + row] = flat_img[wg*16+row][t]
    int i = tid * 4;                 // 4 consecutive t of one row
    int m = i >> 8;
    float4v v = *(const float4v*)(flat_img + (size_t)wg * (ROWS*TSTEPS) + i);
    int tbase = i & 255;
    #pragma unroll
    for (int s = 0; s < 4; ++s) x_tr[(tbase + s) * ROWS + m] = v[s];
  }

  { // zero latent: 2 buf x 2 lv x TILE shorts == 2*TILE ints
    int* p0 = (int*)latp;
    for (int i = tid; i < 2 * TILE; i += 1024) p0[i] = 0;
  }

  // persistent W_hh fragments: 2-level fp16 split (level-1 scaled 2^11)
  half8 Wh[8], Wl[8];
  const int g = wv*16 + c;
  const float bias = b_ih[g] + b_hh[g];
  const float wih  = W_ih[g];
  #pragma unroll
  for (int kk = 0; kk < 8; ++kk) {
    const float* wp = W_hh + g*HDIM + kk*32 + q*8;
    float4v w0 = *(const float4v*)wp;
    float4v w1 = *(const float4v*)(wp + 4);
    half8 h8, l8;
    #pragma unroll
    for (int j2 = 0; j2 < 4; ++j2) {
      float f0 = w0[j2], f1 = w1[j2];
      _Float16 h0 = (_Float16)f0, h1 = (_Float16)f1;
      _Float16 l0 = (_Float16)((f0 - (float)h0) * 2048.0f);
      _Float16 l1 = (_Float16)((f1 - (float)h1) * 2048.0f);
      h8[j2] = h0; h8[j2+4] = h1;
      l8[j2] = l0; l8[j2+4] = l1;
    }
    Wh[kk] = h8; Wl[kk] = l8;
  }

  // fp32 master latent: lane owns rows q*4+r (r<4), col g
  float lat[4]  = {0.f, 0.f, 0.f, 0.f};
  // pipelined noise for the CURRENT step (generated during the previous one);
  // t=0 uses zeros with esc[0]==0 -> fmaf(0,0,lat)==lat, bit-exact.
  float nrmv[4] = {0.f, 0.f, 0.f, 0.f};
  const unsigned jbase = ((unsigned)(wg*ROWS + q*4) << 8) + (unsigned)g;

  // In-block slot-rotated layout: col -> (b=col>>5, sl=(col>>3)&3, j=col&7),
  // stored at row*LSTR + b*32 + ((sl + (row>>2))&3)*8 + j.
  // Read (row=c, block kk, orig slot q): stored slot (q+(c>>2))&3; rb+kk*32
  // walks blocks; no wrap (max in-row offset 255). Write (rows 4q+r, col g):
  // rotation q, r-independent -> per-lane constant woff; banks = exact 2-way.
  const int aoff = c * LSTR + ((q + (c >> 2)) & 3) * 8;
  const int wsl  = ((wv & 1) * 2 + (c >> 3) + q) & 3;   // stored slot of col g
  const int woff = (q*4) * LSTR + (wv >> 1) * 32 + wsl * 8 + (c & 7);

  __syncthreads();

  for (int t = 0; t < TSTEPS; ++t) {
    // apply the noise generated last step (keys[2t] pairing preserved)
    float escale = esc_sh[t];
    #pragma unroll
    for (int r = 0; r < 4; ++r) lat[r] = fmaf(escale, nrmv[r], lat[r]);

    // keys for NEXT step's noise (pipelined across the barrier)
    unsigned kA = (unsigned)__builtin_amdgcn_readfirstlane((int)keys_sh[2*t+2]);
    unsigned kB = (unsigned)__builtin_amdgcn_readfirstlane((int)keys_sh[2*t+3]);

    // x for rows q*4..q*4+3 at time t: one broadcast ds_read_b128
    float4v xv = *(const float4v*)&x_tr[t * ROWS + q * 4];

    const short* rb = latp + (t & 1) * (2*TILE) + aoff;
    short*       wb = latp + ((t + 1) & 1) * (2*TILE) + woff;

    // AhWh -> aa ; (AlWh + AhWl) -> ab (one 2^11 scale); drop AlWl ~2^-24.
    // One cipher+erfinv for step t+1 interleaved per kk (kk<4): this VALU
    // work has no LDS/MFMA deps, so it covers the frag-read lgkmcnt stalls.
    float4v aa = {0.f, 0.f, 0.f, 0.f};
    float4v ab = {0.f, 0.f, 0.f, 0.f};
    #pragma unroll
    for (int kk = 0; kk < 8; ++kk) {
      half8 ah = *(const half8*)(rb + 0*TILE + kk*32);
      half8 al = *(const half8*)(rb + 1*TILE + kk*32);
      aa = mfma_f16(ah, Wh[kk], aa);
      ab = mfma_f16(al, Wh[kk], ab);
      ab = mfma_f16(ah, Wl[kk], ab);
      if (kk < 4) {  // compile-time uniform: no divergence
        unsigned j = jbase + ((unsigned)kk << 8);  // b = wg*16+q*4+kk
        U2 rr = threefry(kA, kB, 0u, j);
        nrmv[kk] = jax_normal_from_bits(rr.x ^ rr.y);  // applied at t+1
      }
    }

    #pragma unroll
    for (int r = 0; r < 4; ++r) {
      float d = aa[r] + ab[r] * (1.0f / 2048.0f);
      float pre = d + fmaf(xv[r], wih, bias);
      float h;
      if (__builtin_fabsf(pre) >= 7.90531110763549805f) {
        h = pre > 0.0f ? 1.0f : -1.0f;     // XLA tanh clamp
      } else {
        float e = __builtin_amdgcn_exp2f(pre * 2.8853900817779268f);
        h = fmaf(-2.0f, __builtin_amdgcn_rcpf(e + 1.0f), 1.0f);
      }
      float nl = lat[r] + xv[r] + h;       // noise already folded into lat
      lat[r] = nl;
      _Float16 hh = (_Float16)nl;          // RNE
      _Float16 ll = (_Float16)((nl - (float)hh) * 2048.0f);
      short* wp = wb + r*LSTR;
      wp[0]    = __builtin_bit_cast(short, hh);
      wp[TILE] = __builtin_bit_cast(short, ll);
    }
    __syncthreads(); // single barrier/step (reads buf t&1, writes (t+1)&1)
  }

  #pragma unroll
  for (int r = 0; r < 4; ++r)
    out[jbase + ((unsigned)r << 8)] = lat[r];
}

extern "C" void kernel_launch(void* const* d_in, const int* in_sizes, int n_in,
                              void* d_out, int out_size, void* d_ws, size_t ws_size,
                              hipStream_t stream) {
  // inputs: [0]=T (int, =256), [1]=flat_img (4096x256 f32), [2]=W_ih (256x1),
  // [3]=W_hh (256x256), [4]=b_ih (256), [5]=b_hh (256)
  (void)in_sizes; (void)n_in; (void)out_size; (void)d_ws; (void)ws_size;
  const float* flat_img = (const float*)d_in[1];
  const float* W_ih     = (const float*)d_in[2];
  const float* W_hh     = (const float*)d_in[3];
  const float* b_ih     = (const float*)d_in[4];
  const float* b_hh     = (const float*)d_in[5];
  drnet_fused<<<dim3(4096 / ROWS), dim3(1024), 0, stream>>>(
      flat_img, W_ih, W_hh, b_ih, b_hh, (float*)d_out);
}